// Round 2
// 416.552 us; speedup vs baseline: 1.0267x; 1.0267x over previous
//
#include <hip/hip_runtime.h>
#include <stdint.h>

#define S 16384
#define D 4096
#define NE 64
#define CAP 320
#define WQ 4               // waves per block = K-quarters
#define KCH (D / WQ)       // 1024 K per wave
#define KSTEPS (KCH / 16)  // 64 mfma k-steps per wave
#define NKS (D / 16)       // 256 total k-steps
#define K2ROWS 128
#define NB (S / K2ROWS)    // 128

typedef _Float16 f16x8 __attribute__((ext_vector_type(8)));
typedef float f32x16 __attribute__((ext_vector_type(16)));

__device__ __forceinline__ uint32_t rotl32(uint32_t v, int n) {
  return (v << n) | (v >> (32 - n));
}

// Bit-exact jax threefry for jax.random.uniform(jax.random.key(1), (S,), f32)
// under jax_threefry_partitionable=True (default since JAX 0.5.0).
// (This exact routine passed the harness in the fp32-VALU baseline.)
__device__ uint32_t threefry_bits(int i) {
  const uint32_t k0 = 0u, k1 = 1u;
  const uint32_t ks2 = k0 ^ k1 ^ 0x1BD11BDAu;
  uint32_t x0 = 0u + k0;
  uint32_t x1 = (uint32_t)i + k1;
#define TFR(R) { x0 += x1; x1 = rotl32(x1, R); x1 ^= x0; }
  TFR(13) TFR(15) TFR(26) TFR(6)
  x0 += k1;  x1 += ks2 + 1u;
  TFR(17) TFR(29) TFR(16) TFR(24)
  x0 += ks2; x1 += k0 + 2u;
  TFR(13) TFR(15) TFR(26) TFR(6)
  x0 += k0;  x1 += k1 + 3u;
  TFR(17) TFR(29) TFR(16) TFR(24)
  x0 += k1;  x1 += ks2 + 4u;
  TFR(13) TFR(15) TFR(26) TFR(6)
  x0 += ks2; x1 += k0 + 5u;
#undef TFR
  return x0 ^ x1;
}

// ---- k0: pack W (64x4096 f32) into fp16 hi/lo MFMA B-fragments.
// Fragment order for v_mfma_f32_32x32x16_f16, n-tile t (cols 32t..32t+31),
// k-step ks: lane l holds col = 32t+(l&31), k = 16*ks + 8*(l>>5) + j.
// The same (lane,j)->k bijection is used for the A fragment; dot products
// are k-permutation invariant as long as A and B agree (CDNA A/B layouts
// are mirror-symmetric). Only the C/D layout must match HW exactly.
// Split: w = wh + wl*2^-12, wh = fp16(w), wl = fp16((w - wh)*4096).
__global__ __launch_bounds__(256) void k0_packw(const float* __restrict__ Wg,
                                                f16x8* __restrict__ WH,
                                                f16x8* __restrict__ WL) {
  const int tid = blockIdx.x * 256 + threadIdx.x;  // 32768 = 256 ks * 2 t * 64 lanes
  const int lane = tid & 63;
  const int t = (tid >> 6) & 1;
  const int ks = tid >> 7;
  const int col = 32 * t + (lane & 31);
  const int k0 = ks * 16 + 8 * (lane >> 5);
  const float* wp = Wg + (size_t)col * D + k0;
  f16x8 h, l;
#pragma unroll
  for (int j = 0; j < 8; ++j) {
    const float w = wp[j];
    const _Float16 wh = (_Float16)w;
    const float r = (w - (float)wh) * 4096.0f;  // exact in f32
    h[j] = wh;
    l[j] = (_Float16)r;
  }
  WH[tid] = h;
  WL[tid] = l;
}

// ---- k1: fused logits GEMM + softmax + top-2 + RNG.
// Split-fp16 MFMA: logits = xh*wh + (xl*wh + xh*wl)*2^-12 (~1e-7 rel, below
// the fp32-reorder noise the passing baseline already exhibited vs JAX).
// Block = 4 waves over the SAME 32 rows; wave w owns K-quarter w (1024 K).
// No cross-wave x reuse -> stream global->reg->convert->MFMA, no staging.
// Partials (32x64 f32 per wave) land in LDS, reduced in deterministic order
// q0+q1+q2+q3, then each wave runs the baseline's verified softmax/top-2/
// threefry logic on 8 rows. Grid = 512 blocks = 2/CU = 8 waves/CU.
__global__ __launch_bounds__(256) void k1_fused(const float* __restrict__ x,
                                                const f16x8* __restrict__ WH,
                                                const f16x8* __restrict__ WL,
                                                int* __restrict__ E1, int* __restrict__ E2,
                                                int* __restrict__ WANT,
                                                float* __restrict__ G1, float* __restrict__ G2) {
  __shared__ float lsum[WQ][32][64];  // 32 KB
  const int w = threadIdx.x >> 6;     // K-quarter
  const int lane = threadIdx.x & 63;
  const int rowBase = blockIdx.x * 32;
  const int row = rowBase + (lane & 31);
  // A fragment source: lane holds x[row][kOff + 16*s + 8*(lane>>5) + j]
  const float* xp = x + (size_t)row * D + w * KCH + (lane >> 5) * 8;
  const int ks0 = w * KSTEPS;

  f32x16 acc0[2], acc1[2];
#pragma unroll
  for (int t = 0; t < 2; ++t)
#pragma unroll
    for (int r = 0; r < 16; ++r) { acc0[t][r] = 0.0f; acc1[t][r] = 0.0f; }

  float4 a0 = *(const float4*)(xp);
  float4 a1 = *(const float4*)(xp + 4);
#pragma unroll 2
  for (int s = 0; s < KSTEPS; ++s) {
    const int sn = (s + 1 < KSTEPS) ? s + 1 : s;  // clamped prefetch (no OOB)
    const float4 a0n = *(const float4*)(xp + sn * 16);
    const float4 a1n = *(const float4*)(xp + sn * 16 + 4);
    const size_t fi = (size_t)(ks0 + s) * 128 + lane;
    const f16x8 bh0 = WH[fi];
    const f16x8 bh1 = WH[fi + 64];
    const f16x8 bl0 = WL[fi];
    const f16x8 bl1 = WL[fi + 64];

    const float af[8] = {a0.x, a0.y, a0.z, a0.w, a1.x, a1.y, a1.z, a1.w};
    f16x8 ah, al;
#pragma unroll
    for (int j = 0; j < 8; ++j) {
      const _Float16 h = (_Float16)af[j];
      ah[j] = h;
      al[j] = (_Float16)((af[j] - (float)h) * 4096.0f);
    }

    acc0[0] = __builtin_amdgcn_mfma_f32_32x32x16_f16(ah, bh0, acc0[0], 0, 0, 0);
    acc1[0] = __builtin_amdgcn_mfma_f32_32x32x16_f16(al, bh0, acc1[0], 0, 0, 0);
    acc1[0] = __builtin_amdgcn_mfma_f32_32x32x16_f16(ah, bl0, acc1[0], 0, 0, 0);
    acc0[1] = __builtin_amdgcn_mfma_f32_32x32x16_f16(ah, bh1, acc0[1], 0, 0, 0);
    acc1[1] = __builtin_amdgcn_mfma_f32_32x32x16_f16(al, bh1, acc1[1], 0, 0, 0);
    acc1[1] = __builtin_amdgcn_mfma_f32_32x32x16_f16(ah, bl1, acc1[1], 0, 0, 0);

    a0 = a0n; a1 = a1n;
  }

  // C/D layout (HW-verified m74/m101, dtype-independent):
  // col = 32t + (lane&31), row = (reg&3) + 8*(reg>>2) + 4*(lane>>5).
  // LDS writes: per (t,r) both 32-lane halves write consecutive words -> free.
#pragma unroll
  for (int t = 0; t < 2; ++t) {
    const int col = 32 * t + (lane & 31);
#pragma unroll
    for (int r = 0; r < 16; ++r) {
      const int lrow = (r & 3) + 8 * (r >> 2) + 4 * (lane >> 5);
      lsum[w][lrow][col] = acc0[t][r] + acc1[t][r] * (1.0f / 4096.0f);
    }
  }
  __syncthreads();

  // Reduce quarters into plane 0, deterministic order ((q0+q1)+q2)+q3.
  // idx = tid + 256*j: consecutive lanes -> consecutive banks, conflict-free.
  {
    float* p0 = &lsum[0][0][0];
    const float* p1 = &lsum[1][0][0];
    const float* p2 = &lsum[2][0][0];
    const float* p3 = &lsum[3][0][0];
#pragma unroll
    for (int j = 0; j < 8; ++j) {
      const int idx = threadIdx.x + 256 * j;
      p0[idx] = ((p0[idx] + p1[idx]) + p2[idx]) + p3[idx];
    }
  }
  __syncthreads();

  // Softmax + top-2 + RNG (baseline k1b body, verbatim logic).
  // Wave w handles rows w*8 .. w*8+7; lane = expert.
  for (int rr = 0; rr < 8; ++rr) {
    const int lrow = w * 8 + rr;
    const int grow = rowBase + lrow;
    const float l = lsum[0][lrow][lane];

    float m = l;
#pragma unroll
    for (int off = 32; off; off >>= 1) m = fmaxf(m, __shfl_xor(m, off));
    const float ex = expf(l - m);
    float ssum = ex;
#pragma unroll
    for (int off = 32; off; off >>= 1) ssum += __shfl_xor(ssum, off);
    ssum = __shfl(ssum, 0);  // single denominator like the reference
    const float gate = ex / ssum;

    // top-1: max value, tie -> lower lane
    float v = gate; int id = lane;
#pragma unroll
    for (int off = 32; off; off >>= 1) {
      float vo = __shfl_xor(v, off); int io = __shfl_xor(id, off);
      if (vo > v || (vo == v && io < id)) { v = vo; id = io; }
    }
    const float g1 = v; const int e1 = id;
    const float gate2 = (lane == e1) ? -1.0f : gate;
    v = gate2; id = lane;
#pragma unroll
    for (int off = 32; off; off >>= 1) {
      float vo = __shfl_xor(v, off); int io = __shfl_xor(id, off);
      if (vo > v || (vo == v && io < id)) { v = vo; id = io; }
    }
    const float g2 = v; const int e2 = id;

    if (lane == 0) {
      const float denom = g1 + g2;
      const float g1n = g1 / denom;
      const float g2n = g2 / denom;
      const uint32_t bits = threefry_bits(grow);
      const float rnd = __uint_as_float((bits >> 9) | 0x3f800000u) - 1.0f;
      E1[grow] = e1; E2[grow] = e2;
      WANT[grow] = (rnd < 2.0f * g2n) ? 1 : 0;
      G1[grow] = g1n; G2[grow] = g2n;
    }
  }
}

// ---- K2: per-block (128 rows) local ranks + histograms for both streams.
__global__ __launch_bounds__(K2ROWS) void k2_rank(const int* __restrict__ E1,
                                                  const int* __restrict__ E2,
                                                  const int* __restrict__ WANT,
                                                  int* __restrict__ LR1, int* __restrict__ LR2,
                                                  int* __restrict__ H1, int* __restrict__ H2) {
  __shared__ unsigned char s1[K2ROWS], s2[K2ROWS];
  __shared__ int h1[NE], h2[NE];
  const int b = blockIdx.x, t = threadIdx.x;
  const int r = b * K2ROWS + t;
  if (t < NE) { h1[t] = 0; h2[t] = 0; }
  const int e1 = E1[r];
  const int e2 = WANT[r] ? E2[r] : NE;  // sentinel = excluded
  s1[t] = (unsigned char)e1;
  s2[t] = (unsigned char)e2;
  __syncthreads();
  int r1 = 0, r2 = 0;
  for (int j = 0; j < t; ++j) {
    r1 += (s1[j] == e1);
    r2 += (s2[j] == e2);
  }
  LR1[r] = r1; LR2[r] = r2;
  atomicAdd(&h1[e1], 1);
  if (e2 < NE) atomicAdd(&h2[e2], 1);
  __syncthreads();
  if (t < NE) { H1[b * NE + t] = h1[t]; H2[b * NE + t] = h2[t]; }
}

// ---- K3: exclusive prefix over blocks per expert + counts1 -> remaining cap2.
__global__ void k3_prefix(const int* __restrict__ H1, const int* __restrict__ H2,
                          int* __restrict__ OFF1, int* __restrict__ OFF2,
                          int* __restrict__ REM2) {
  const int e = threadIdx.x;  // 64 threads
  int run1 = 0, run2 = 0;
  for (int b = 0; b < NB; ++b) {
    OFF1[b * NE + e] = run1; run1 += H1[b * NE + e];
    OFF2[b * NE + e] = run2; run2 += H2[b * NE + e];
  }
  REM2[e] = CAP - min(run1, CAP);
}

// ---- K4: apply capacity decisions, scatter into (pre-zeroed) combine.
__global__ __launch_bounds__(256) void k4_scatter(const int* __restrict__ E1,
                                                  const int* __restrict__ E2,
                                                  const int* __restrict__ WANT,
                                                  const float* __restrict__ G1,
                                                  const float* __restrict__ G2,
                                                  const int* __restrict__ LR1,
                                                  const int* __restrict__ LR2,
                                                  const int* __restrict__ OFF1,
                                                  const int* __restrict__ OFF2,
                                                  const int* __restrict__ REM2,
                                                  float* __restrict__ out) {
  const int r = blockIdx.x * 256 + threadIdx.x;
  const int b = r / K2ROWS;
  const int e1 = E1[r];
  const int pos1 = OFF1[b * NE + e1] + LR1[r] + 1;
  if (pos1 <= CAP) out[(size_t)r * NE + e1] = G1[r];
  if (WANT[r]) {
    const int e2 = E2[r];
    const int pos2 = OFF2[b * NE + e2] + LR2[r] + 1;
    if (pos2 <= REM2[e2]) out[(size_t)r * NE + e2] = G2[r];
  }
}

extern "C" void kernel_launch(void* const* d_in, const int* in_sizes, int n_in,
                              void* d_out, int out_size, void* d_ws, size_t ws_size,
                              hipStream_t stream) {
  const float* x  = (const float*)d_in[0];
  const float* Wg = (const float*)d_in[1];
  float* out = (float*)d_out;
  char* ws = (char*)d_ws;

  size_t off = 0;
  int*   E1   = (int*)(ws + off);   off += (size_t)S * 4;
  int*   E2   = (int*)(ws + off);   off += (size_t)S * 4;
  int*   WANT = (int*)(ws + off);   off += (size_t)S * 4;
  float* G1   = (float*)(ws + off); off += (size_t)S * 4;
  float* G2   = (float*)(ws + off); off += (size_t)S * 4;
  int*   LR1  = (int*)(ws + off);   off += (size_t)S * 4;
  int*   LR2  = (int*)(ws + off);   off += (size_t)S * 4;
  int*   H1   = (int*)(ws + off);   off += (size_t)NB * NE * 4;
  int*   H2   = (int*)(ws + off);   off += (size_t)NB * NE * 4;
  int*   OFF1 = (int*)(ws + off);   off += (size_t)NB * NE * 4;
  int*   OFF2 = (int*)(ws + off);   off += (size_t)NB * NE * 4;
  int*   REM2 = (int*)(ws + off);   off += (size_t)NE * 4;
  f16x8* WH   = (f16x8*)(ws + off); off += (size_t)NKS * 2 * 64 * sizeof(f16x8);  // 512 KB
  f16x8* WL   = (f16x8*)(ws + off); off += (size_t)NKS * 2 * 64 * sizeof(f16x8);  // 512 KB

  hipMemsetAsync(d_out, 0, (size_t)out_size * sizeof(float), stream);
  k0_packw<<<128, 256, 0, stream>>>(Wg, WH, WL);
  k1_fused<<<S / 32, 256, 0, stream>>>(x, WH, WL, E1, E2, WANT, G1, G2);
  k2_rank<<<NB, K2ROWS, 0, stream>>>(E1, E2, WANT, LR1, LR2, H1, H2);
  k3_prefix<<<1, NE, 0, stream>>>(H1, H2, OFF1, OFF2, REM2);
  k4_scatter<<<S / 256, 256, 0, stream>>>(E1, E2, WANT, G1, G2, LR1, LR2, OFF1, OFF2, REM2, out);
}